// Round 15
// baseline (84.988 us; speedup 1.0000x reference)
//
#include <hip/hip_runtime.h>
#include <hip/hip_bf16.h>

#define TT 2048
#define DDIM 1024
#define NHEAD 16
#define HD 64
#define KVBLK 64

typedef float f32x4 __attribute__((ext_vector_type(4)));
typedef short bf16x8 __attribute__((ext_vector_type(8)));

__device__ __forceinline__ ushort f2bf(float f) {
    __hip_bfloat16 h = __float2bfloat16(f);
    return *reinterpret_cast<ushort*>(&h);
}

// barrier WITHOUT the compiler's vmcnt(0) drain (R11-proven: main 84->62us).
__device__ __forceinline__ void barrier_lgkm_only() {
    asm volatile("s_waitcnt lgkmcnt(0)" ::: "memory");
    __builtin_amdgcn_s_barrier();
}

// ============ pre-pass (R8-proven): K -> bf16, V -> bf16 transposed ============
__global__ __launch_bounds__(256)
void prepass_kernel(const float* __restrict__ kg, const float* __restrict__ vg,
                    ushort* __restrict__ kbf, ushort* __restrict__ vt) {
    __shared__ float vtile[64][65];
    const int tid = threadIdx.x;
    const int kv0 = (int)blockIdx.x * 64;
    const int bh  = (int)blockIdx.y;
    const int b = bh >> 4, h = bh & 15;
    const int row = tid >> 2;
    const int c0  = (tid & 3) * 16;
    const size_t gin = ((size_t)(b * TT + kv0 + row)) * DDIM + h * HD + c0;

    {
        ushort o[16];
        #pragma unroll
        for (int i = 0; i < 4; ++i) {
            float4 a = *(const float4*)(kg + gin + i * 4);
            o[i*4+0]=f2bf(a.x); o[i*4+1]=f2bf(a.y); o[i*4+2]=f2bf(a.z); o[i*4+3]=f2bf(a.w);
        }
        ushort* kout = kbf + ((size_t)bh * TT + kv0 + row) * HD + c0;
        *(bf16x8*)kout       = *(bf16x8*)&o[0];
        *(bf16x8*)(kout + 8) = *(bf16x8*)&o[8];
    }
    #pragma unroll
    for (int i = 0; i < 4; ++i) {
        float4 a = *(const float4*)(vg + gin + i * 4);
        vtile[row][c0 + i*4 + 0] = a.x;
        vtile[row][c0 + i*4 + 1] = a.y;
        vtile[row][c0 + i*4 + 2] = a.z;
        vtile[row][c0 + i*4 + 3] = a.w;
    }
    __syncthreads();
    {
        ushort o[16];
        #pragma unroll
        for (int i = 0; i < 16; ++i) o[i] = f2bf(vtile[c0 + i][row]);
        ushort* vout = vt + ((size_t)bh * HD + row) * TT + kv0 + c0;
        *(bf16x8*)vout       = *(bf16x8*)&o[0];
        *(bf16x8*)(vout + 8) = *(bf16x8*)&o[8];
    }
}

// ============ main: QBLK=128 (two q-sets/wave), R11 pipeline ============
// One staged 64-row K/V tile feeds 32 MFMA/wave-iter and two INDEPENDENT
// softmax chains (ILP). Staging+barrier per kv-element halves vs R11.
// Grid 512: CU slot s gets {qt=15-s, qt=s} -> 34 iters on every CU.
__global__ __launch_bounds__(256, 2)
void attn_main(const float* __restrict__ qg, const ushort* __restrict__ kbf,
               const ushort* __restrict__ vt, float* __restrict__ out) {
    __shared__ __align__(16) ushort lds_k[2][KVBLK * HD];
    __shared__ __align__(16) ushort lds_v[2][HD * KVBLK];
    __shared__ __align__(16) ushort lds_p[4][2][16 * 64];

    const int tid  = threadIdx.x;
    const int wv   = tid >> 6;
    const int lane = tid & 63;
    const int hi   = lane >> 4;
    const int qr   = lane & 15;

    // XCD decode (R6-proven) + balanced pairing over 128-row q-tiles
    const int flat = (int)blockIdx.x;          // 0..511
    const int xcd  = flat & 7;
    const int idx  = flat >> 3;                // 0..63
    const int bs   = idx >> 4;                 // 0..3
    const int s    = idx & 15;                 // 0..15
    const int bh   = xcd * 4 + bs;
    const int qt   = (bs & 1) ? s : (15 - s);  // 128-row tile index
    const int b    = bh >> 4;
    const int h    = bh & 15;
    const int q0   = qt * 128;

    const float LOG2E  = 1.4426950408889634f;
    const float slope2 = exp2f(-0.5f * (float)(h + 1)) * LOG2E;
    const float sc2    = 0.125f * LOG2E;
    float c2[16];
    #pragma unroll
    for (int st = 0; st < 4; ++st)
        #pragma unroll
        for (int rr = 0; rr < 4; ++rr) c2[st * 4 + rr] = (float)(st * 16 + rr) * slope2;

    // ---- Q fragments, both sets ----
    bf16x8 qf0[2], qf1[2];
    {
        const float* gq0 = qg + ((size_t)(b * TT + q0 + wv * 16 + qr)) * DDIM + h * HD + hi * 8;
        const float* gq1 = gq0 + (size_t)64 * DDIM;
        #pragma unroll
        for (int ch = 0; ch < 2; ++ch) {
            float4 a0 = *(const float4*)(gq0 + ch * 32);
            float4 a1 = *(const float4*)(gq0 + ch * 32 + 4);
            bf16x8 w;
            w[0]=f2bf(a0.x); w[1]=f2bf(a0.y); w[2]=f2bf(a0.z); w[3]=f2bf(a0.w);
            w[4]=f2bf(a1.x); w[5]=f2bf(a1.y); w[6]=f2bf(a1.z); w[7]=f2bf(a1.w);
            qf0[ch] = w;
            float4 b0 = *(const float4*)(gq1 + ch * 32);
            float4 b1 = *(const float4*)(gq1 + ch * 32 + 4);
            bf16x8 u;
            u[0]=f2bf(b0.x); u[1]=f2bf(b0.y); u[2]=f2bf(b0.z); u[3]=f2bf(b0.w);
            u[4]=f2bf(b1.x); u[5]=f2bf(b1.y); u[6]=f2bf(b1.z); u[7]=f2bf(b1.w);
            qf1[ch] = u;
        }
    }

    const ushort* kb = kbf + (size_t)bh * TT * HD;
    const ushort* vb = vt  + (size_t)bh * HD * TT;

    const int srow = tid >> 2;
    const int sci  = tid & 3;
    const int sw   = srow & 7;

    bf16x8 kr0, kr1, vr0, vr1;
    auto stage_issue = [&](int kv0) {
        const ushort* kp = kb + (size_t)(kv0 + srow) * HD + sci * 8;
        kr0 = *(const bf16x8*)kp;
        kr1 = *(const bf16x8*)(kp + 32);
        const ushort* vp = vb + (size_t)srow * TT + kv0 + sci * 8;
        vr0 = *(const bf16x8*)vp;
        vr1 = *(const bf16x8*)(vp + 32);
    };
    auto stage_write = [&](int nb) {
        *(bf16x8*)&lds_k[nb][srow * 64 + ((sci ^ sw) << 3)]       = kr0;
        *(bf16x8*)&lds_k[nb][srow * 64 + (((sci + 4) ^ sw) << 3)] = kr1;
        *(bf16x8*)&lds_v[nb][srow * 64 + ((sci ^ sw) << 3)]       = vr0;
        *(bf16x8*)&lds_v[nb][srow * 64 + (((sci + 4) ^ sw) << 3)] = vr1;
    };

    f32x4 oacc0[4] = {}, oacc1[4] = {};
    float mrun0 = -INFINITY, lrun0 = 0.f;
    float mrun1 = -INFINITY, lrun1 = 0.f;
    const int ti0 = q0 + wv * 16 + qr;
    const int ti1 = ti0 + 64;
    const int nit = 2 * qt + 2;

    // one q-set's full per-tile update (QK -> softmax -> P -> PV)
    auto compute_set = [&](int buf, int kv0, bool diag, int pslot,
                           bf16x8* qf, f32x4* oacc, float& mrun, float& lrun, int ti) {
        f32x4 sa[4] = {};
        __builtin_amdgcn_s_setprio(1);
        #pragma unroll
        for (int st = 0; st < 4; ++st) {
            if (!diag || st <= wv) {
                const int krow = st * 16 + qr;
                const int ksw = (krow & 7);
                bf16x8 k0 = *(const bf16x8*)&lds_k[buf][krow * 64 + ((hi ^ ksw) << 3)];
                bf16x8 k1 = *(const bf16x8*)&lds_k[buf][krow * 64 + (((4 + hi) ^ ksw) << 3)];
                sa[st] = __builtin_amdgcn_mfma_f32_16x16x32_bf16(k0, qf[0], sa[st], 0, 0, 0);
                sa[st] = __builtin_amdgcn_mfma_f32_16x16x32_bf16(k1, qf[1], sa[st], 0, 0, 0);
            }
        }
        __builtin_amdgcn_s_setprio(0);

        const float relb  = (float)(kv0 - ti + hi * 4);
        const float relb2 = relb * slope2;
        float xv[16];
        float tm = -INFINITY;
        #pragma unroll
        for (int st = 0; st < 4; ++st)
            #pragma unroll
            for (int rr = 0; rr < 4; ++rr) {
                float v = fmaf(sa[st][rr], sc2, relb2 + c2[st * 4 + rr]);
                if (diag) {
                    const float rel = relb + (float)(st * 16 + rr);   // exact small ints
                    v = (rel <= 0.f) ? v : -INFINITY;
                }
                xv[st * 4 + rr] = v;
                tm = fmaxf(tm, v);
            }
        if (!__all(tm <= mrun + 8.f)) {
            tm = fmaxf(tm, __shfl_xor(tm, 16));
            tm = fmaxf(tm, __shfl_xor(tm, 32));
            const float mnew = fmaxf(mrun, tm);
            const float fsc  = exp2f(mrun - mnew);
            mrun = mnew;
            lrun *= fsc;
            float fo[4];
            #pragma unroll
            for (int rr = 0; rr < 4; ++rr) fo[rr] = __shfl(fsc, hi * 4 + rr);
            #pragma unroll
            for (int dt = 0; dt < 4; ++dt)
                #pragma unroll
                for (int rr = 0; rr < 4; ++rr) oacc[dt][rr] *= fo[rr];
        }
        float psum = 0.f;
        #pragma unroll
        for (int i = 0; i < 16; ++i) { xv[i] = exp2f(xv[i] - mrun); psum += xv[i]; }
        lrun += psum;

        #pragma unroll
        for (int st = 0; st < 4; ++st) {
            ushort4 w;
            w.x = f2bf(xv[st * 4 + 0]); w.y = f2bf(xv[st * 4 + 1]);
            w.z = f2bf(xv[st * 4 + 2]); w.w = f2bf(xv[st * 4 + 3]);
            const int slot8 = (st << 1) | (hi >> 1);
            *(ushort4*)&lds_p[wv][pslot][qr * 64 + ((slot8 ^ (qr & 7)) << 3) + ((hi & 1) << 2)] = w;
        }

        __builtin_amdgcn_s_setprio(1);
        #pragma unroll
        for (int ks = 0; ks < 2; ++ks) {
            if (!diag || wv >= 2 || ks == 0) {
                bf16x8 pa = *(const bf16x8*)&lds_p[wv][pslot][qr * 64 + ((((ks << 2) | hi) ^ (qr & 7)) << 3)];
                #pragma unroll
                for (int dt = 0; dt < 4; ++dt) {
                    const int dv = dt * 16 + qr;
                    bf16x8 vbf = *(const bf16x8*)&lds_v[buf][dv * 64 + ((((ks << 2) + hi) ^ (dv & 7)) << 3)];
                    oacc[dt] = __builtin_amdgcn_mfma_f32_16x16x32_bf16(pa, vbf, oacc[dt], 0, 0, 0);
                }
            }
        }
        __builtin_amdgcn_s_setprio(0);
    };

    stage_issue(q0 + 64);   // top tile (set1's diagonal)
    stage_write(0);

    for (int j = 0; j < nit; ++j) {
        const int buf = j & 1;
        const int kv0 = q0 + 64 - j * KVBLK;        // descending
        if (j + 1 < nit) stage_issue(kv0 - KVBLK);  // in flight ACROSS barrier
        barrier_lgkm_only();

        // set1 always active; diag at j==0. set0 active j>=1; diag at j==1.
        compute_set(buf, kv0, j == 0, 1, qf1, oacc1, mrun1, lrun1, ti1);
        if (j >= 1)
            compute_set(buf, kv0, j == 1, 0, qf0, oacc0, mrun0, lrun0, ti0);

        if (j + 1 < nit) stage_write(buf ^ 1);      // vmcnt wait lands here
    }

    // ---- epilogue, both sets ----
    {
        float lr0 = lrun0, lr1 = lrun1;
        lr0 += __shfl_xor(lr0, 16); lr0 += __shfl_xor(lr0, 32);
        lr1 += __shfl_xor(lr1, 16); lr1 += __shfl_xor(lr1, 32);
        const float li0 = 1.0f / lr0, li1 = 1.0f / lr1;
        #pragma unroll
        for (int rr = 0; rr < 4; ++rr) {
            const float i0 = __shfl(li0, hi * 4 + rr);
            const float i1 = __shfl(li1, hi * 4 + rr);
            float* g0 = out + ((size_t)(b * TT + q0 + wv * 16 + hi * 4 + rr)) * DDIM + h * HD;
            float* g1 = g0 + (size_t)64 * DDIM;
            #pragma unroll
            for (int dt = 0; dt < 4; ++dt) {
                g0[dt * 16 + qr] = oacc0[dt][rr] * i0;
                g1[dt * 16 + qr] = oacc1[dt][rr] * i1;
            }
        }
    }
}

// ============ fallback (R6 kernel, proven 76.5us) if ws too small ============
#define QBLK 64
#define NQT (TT / QBLK)
#define VST 72
__global__ __launch_bounds__(256, 2)
void alibi_attn_fallback(const float* __restrict__ qg,
                         const float* __restrict__ kg,
                         const float* __restrict__ vg,
                         float* __restrict__ out) {
    __shared__ __align__(16) ushort lds_k[KVBLK * HD];
    __shared__ __align__(16) ushort lds_vt[HD * VST];
    __shared__ __align__(16) ushort lds_p[4][16 * 64];

    const int tid  = threadIdx.x;
    const int wv   = tid >> 6;
    const int lane = tid & 63;
    const int hi   = lane >> 4;
    const int qr   = lane & 15;

    const int flat = (int)blockIdx.x;
    const int xcd  = flat & 7;
    const int idx  = flat >> 3;
    const int bh   = xcd * 4 + (idx >> 5);
    const int qt   = NQT - 1 - (idx & 31);
    const int b    = bh >> 4;
    const int h    = bh & 15;
    const int q0   = qt * QBLK;

    const float LOG2E  = 1.4426950408889634f;
    const float slope2 = exp2f(-0.5f * (float)(h + 1)) * LOG2E;
    const float sc2    = 0.125f * LOG2E;

    const size_t bhbase = (size_t)(b * TT) * DDIM + (size_t)(h * HD);

    bf16x8 qf[2];
    {
        const float* gq = qg + bhbase + (size_t)(q0 + wv * 16 + qr) * DDIM + hi * 8;
        #pragma unroll
        for (int ch = 0; ch < 2; ++ch) {
            float4 a0 = *(const float4*)(gq + ch * 32);
            float4 a1 = *(const float4*)(gq + ch * 32 + 4);
            bf16x8 w;
            w[0]=f2bf(a0.x); w[1]=f2bf(a0.y); w[2]=f2bf(a0.z); w[3]=f2bf(a0.w);
            w[4]=f2bf(a1.x); w[5]=f2bf(a1.y); w[6]=f2bf(a1.z); w[7]=f2bf(a1.w);
            qf[ch] = w;
        }
    }

    const int krow = tid >> 3;
    const int kcg  = tid & 7;
    const int vdv  = tid & 63;
    const int vkc  = tid >> 6;

    float ka[2][8], va[2][8];
    auto issue_loads = [&](int kv0) {
        const float* kp0 = kg + bhbase + (size_t)(kv0 + krow) * DDIM + kcg * 8;
        const float* kp1 = kp0 + (size_t)32 * DDIM;
        *(float4*)&ka[0][0] = *(const float4*)kp0; *(float4*)&ka[0][4] = *(const float4*)(kp0 + 4);
        *(float4*)&ka[1][0] = *(const float4*)kp1; *(float4*)&ka[1][4] = *(const float4*)(kp1 + 4);
        const float* vp0 = vg + bhbase + (size_t)(kv0 + vkc * 8) * DDIM + vdv;
        const float* vp1 = vp0 + (size_t)32 * DDIM;
        #pragma unroll
        for (int jj = 0; jj < 8; ++jj) {
            va[0][jj] = vp0[(size_t)jj * DDIM];
            va[1][jj] = vp1[(size_t)jj * DDIM];
        }
    };
    auto write_stage = [&]() {
        #pragma unroll
        for (int s2 = 0; s2 < 2; ++s2) {
            bf16x8 w;
            #pragma unroll
            for (int e = 0; e < 8; ++e) w[e] = f2bf(ka[s2][e]);
            const int row = krow + s2 * 32;
            *(bf16x8*)&lds_k[row * 64 + ((kcg ^ (row & 7)) << 3)] = w;
            bf16x8 u;
            #pragma unroll
            for (int e = 0; e < 8; ++e) u[e] = f2bf(va[s2][e]);
            const int kc = vkc + s2 * 4;
            *(bf16x8*)&lds_vt[vdv * VST + ((kc ^ ((vdv >> 3) & 7)) << 3)] = u;
        }
    };

    const int nit = qt + 1;
    issue_loads(q0);
    write_stage();

    f32x4 oacc[4] = {};
    float mrun = -INFINITY, lrun = 0.f;

    for (int j = 0; j < nit; ++j) {
        const int kv0 = (qt - j) * KVBLK;
        if (j + 1 < nit) issue_loads(kv0 - KVBLK);
        __syncthreads();

        const bool diag = (j == 0);

        f32x4 s_acc[4] = {};
        __builtin_amdgcn_s_setprio(1);
        #pragma unroll
        for (int st = 0; st < 4; ++st) {
            if (!diag || st <= wv) {
                const int kvrow = st * 16 + qr;
                #pragma unroll
                for (int ch = 0; ch < 2; ++ch) {
                    bf16x8 kf = *(const bf16x8*)&lds_k[kvrow * 64 + ((((ch << 2) + hi) ^ (kvrow & 7)) << 3)];
                    s_acc[st] = __builtin_amdgcn_mfma_f32_16x16x32_bf16(kf, qf[ch], s_acc[st], 0, 0, 0);
                }
            }
        }
        __builtin_amdgcn_s_setprio(0);

        const int ti = q0 + wv * 16 + qr;
        float xv[16];
        float tm = -INFINITY;
        {
            const float relb = (float)(kv0 - ti);
            #pragma unroll
            for (int st = 0; st < 4; ++st)
                #pragma unroll
                for (int rr = 0; rr < 4; ++rr) {
                    const float rel = relb + (float)(st * 16 + hi * 4 + rr);
                    float v = s_acc[st][rr] * sc2 + rel * slope2;
                    if (diag) v = (rel <= 0.f) ? v : -INFINITY;
                    xv[st * 4 + rr] = v;
                    tm = fmaxf(tm, v);
                }
        }
        tm = fmaxf(tm, __shfl_xor(tm, 16));
        tm = fmaxf(tm, __shfl_xor(tm, 32));
        if (!__all(tm <= mrun + 8.f)) {
            const float mnew = fmaxf(mrun, tm);
            const float fsc  = exp2f(mrun - mnew);
            mrun = mnew;
            lrun *= fsc;
            float fo[4];
            #pragma unroll
            for (int rr = 0; rr < 4; ++rr) fo[rr] = __shfl(fsc, hi * 4 + rr);
            #pragma unroll
            for (int dt = 0; dt < 4; ++dt)
                #pragma unroll
                for (int rr = 0; rr < 4; ++rr) oacc[dt][rr] *= fo[rr];
        }
        float psum = 0.f;
        #pragma unroll
        for (int i = 0; i < 16; ++i) { xv[i] = exp2f(xv[i] - mrun); psum += xv[i]; }
        lrun += psum;

        #pragma unroll
        for (int st = 0; st < 4; ++st) {
            ushort4 w;
            w.x = f2bf(xv[st * 4 + 0]); w.y = f2bf(xv[st * 4 + 1]);
            w.z = f2bf(xv[st * 4 + 2]); w.w = f2bf(xv[st * 4 + 3]);
            const int slot8 = (st << 1) | (hi >> 1);
            *(ushort4*)&lds_p[wv][qr * 64 + ((slot8 ^ (qr & 7)) << 3) + ((hi & 1) << 2)] = w;
        }

        __builtin_amdgcn_s_setprio(1);
        #pragma unroll
        for (int ks = 0; ks < 2; ++ks) {
            if (!diag || wv >= 2 || ks == 0) {
                bf16x8 pa = *(const bf16x8*)&lds_p[wv][qr * 64 + ((((ks << 2) | hi) ^ (qr & 7)) << 3)];
                #pragma unroll
                for (int dt = 0; dt < 4; ++dt) {
                    const int dv = dt * 16 + qr;
                    bf16x8 vbf = *(const bf16x8*)&lds_vt[dv * VST + ((((ks << 2) + hi) ^ ((dv >> 3) & 7)) << 3)];
                    oacc[dt] = __builtin_amdgcn_mfma_f32_16x16x32_bf16(pa, vbf, oacc[dt], 0, 0, 0);
                }
            }
        }
        __builtin_amdgcn_s_setprio(0);

        if (j + 1 < nit) {
            __syncthreads();
            write_stage();
        }
    }

    {
        float lr = lrun;
        lr += __shfl_xor(lr, 16);
        lr += __shfl_xor(lr, 32);
        const float linv = 1.0f / lr;
        #pragma unroll
        for (int rr = 0; rr < 4; ++rr) {
            const float inv = __shfl(linv, hi * 4 + rr);
            float* go = out + bhbase + (size_t)(q0 + wv * 16 + hi * 4 + rr) * DDIM;
            #pragma unroll
            for (int dt = 0; dt < 4; ++dt)
                go[dt * 16 + qr] = oacc[dt][rr] * inv;
        }
    }
}

extern "C" void kernel_launch(void* const* d_in, const int* in_sizes, int n_in,
                              void* d_out, int out_size, void* d_ws, size_t ws_size,
                              hipStream_t stream) {
    (void)in_sizes; (void)n_in; (void)out_size;
    const float* q = (const float*)d_in[0];
    const float* k = (const float*)d_in[1];
    const float* v = (const float*)d_in[2];
    float* o = (float*)d_out;

    const size_t elems = (size_t)2 * NHEAD * TT * HD;
    const size_t kv_b  = 2 * elems * sizeof(ushort);       // 16.78 MB
    if (ws_size >= kv_b) {
        ushort* kbf = (ushort*)d_ws;
        ushort* vtt = kbf + elems;
        prepass_kernel<<<dim3(32, 32), 256, 0, stream>>>(k, v, kbf, vtt);
        attn_main<<<dim3(512), 256, 0, stream>>>(q, kbf, vtt, o);
    } else {
        alibi_attn_fallback<<<dim3(1024), 256, 0, stream>>>(q, k, v, o);
    }
}

// Round 16
// 67.999 us; speedup vs baseline: 1.2498x; 1.2498x over previous
//
#include <hip/hip_runtime.h>
#include <hip/hip_bf16.h>

#define TT 2048
#define DDIM 1024
#define NHEAD 16
#define HD 64
#define QBLK 64
#define KVBLK 64
#define NQT (TT / QBLK)

typedef float f32x4 __attribute__((ext_vector_type(4)));
typedef short bf16x8 __attribute__((ext_vector_type(8)));

__device__ __forceinline__ ushort f2bf(float f) {
    __hip_bfloat16 h = __float2bfloat16(f);
    return *reinterpret_cast<ushort*>(&h);
}

// barrier WITHOUT the compiler's vmcnt(0) drain (R11-proven: main 84->62us).
__device__ __forceinline__ void barrier_lgkm_only() {
    asm volatile("s_waitcnt lgkmcnt(0)" ::: "memory");
    __builtin_amdgcn_s_barrier();
}

// ============ pre-pass (R8-proven): K -> bf16, V -> bf16 transposed ============
__global__ __launch_bounds__(256)
void prepass_kernel(const float* __restrict__ kg, const float* __restrict__ vg,
                    ushort* __restrict__ kbf, ushort* __restrict__ vt) {
    __shared__ float vtile[64][65];
    const int tid = threadIdx.x;
    const int kv0 = (int)blockIdx.x * 64;
    const int bh  = (int)blockIdx.y;
    const int b = bh >> 4, h = bh & 15;
    const int row = tid >> 2;
    const int c0  = (tid & 3) * 16;
    const size_t gin = ((size_t)(b * TT + kv0 + row)) * DDIM + h * HD + c0;

    {
        ushort o[16];
        #pragma unroll
        for (int i = 0; i < 4; ++i) {
            float4 a = *(const float4*)(kg + gin + i * 4);
            o[i*4+0]=f2bf(a.x); o[i*4+1]=f2bf(a.y); o[i*4+2]=f2bf(a.z); o[i*4+3]=f2bf(a.w);
        }
        ushort* kout = kbf + ((size_t)bh * TT + kv0 + row) * HD + c0;
        *(bf16x8*)kout       = *(bf16x8*)&o[0];
        *(bf16x8*)(kout + 8) = *(bf16x8*)&o[8];
    }
    #pragma unroll
    for (int i = 0; i < 4; ++i) {
        float4 a = *(const float4*)(vg + gin + i * 4);
        vtile[row][c0 + i*4 + 0] = a.x;
        vtile[row][c0 + i*4 + 1] = a.y;
        vtile[row][c0 + i*4 + 2] = a.z;
        vtile[row][c0 + i*4 + 3] = a.w;
    }
    __syncthreads();
    {
        ushort o[16];
        #pragma unroll
        for (int i = 0; i < 16; ++i) o[i] = f2bf(vtile[c0 + i][row]);
        ushort* vout = vt + ((size_t)bh * HD + row) * TT + kv0 + c0;
        *(bf16x8*)vout       = *(bf16x8*)&o[0];
        *(bf16x8*)(vout + 8) = *(bf16x8*)&o[8];
    }
}

// ============ split main: 32KB LDS (P aliased into idle V buffer) ============
// P slot of wave w == wave w's own V-staging region (tid>>2 ∈ [16w,16w+16)),
// and lds_v[buf^1] is idle from barrier until stage_write at iter end ->
// P-write, P-read(PV), V-stage-write are same-wave in-order LDS ops. 32KB
// -> 5 blocks/CU; 1536-block split grid (heavy halves first) backfills.
__global__ __launch_bounds__(256, 2)
void attn_split(const float* __restrict__ qg, const ushort* __restrict__ kbf,
                const ushort* __restrict__ vtt, float* __restrict__ po,
                float* __restrict__ ml, float* __restrict__ out) {
    __shared__ __align__(16) ushort lds_k[2][KVBLK * HD];
    __shared__ __align__(16) ushort lds_v[2][HD * KVBLK];

    const int tid  = threadIdx.x;
    const int wv   = tid >> 6;
    const int lane = tid & 63;
    const int hi   = lane >> 4;
    const int qr   = lane & 15;

    // R12-proven decode: heavy items (id<32) dispatch first, lights backfill.
    const int flat = (int)blockIdx.x;          // 0..1535
    const int xcd  = flat & 7;
    const int i2   = flat >> 3;                // 0..191
    const int bh   = xcd * 4 + (i2 & 3);
    const int id   = i2 >> 2;                  // 0..47
    int qt, thi, part = 0;
    bool hasdiag, heavy;
    if (id < 16)      { qt = 16 + id;        const int n = qt + 1; thi = n;      hasdiag = true;  heavy = true; part = 0; }
    else if (id < 32) { qt = 31 - (id - 16); const int n = qt + 1; thi = n >> 1; hasdiag = false; heavy = true; part = 1; }
    else              { qt = id - 32;        thi = qt + 1; hasdiag = true; heavy = false; }
    const int lo = (heavy && part == 0) ? ((qt + 1) >> 1) : 0;
    const int nt = thi - lo;
    const int b  = bh >> 4;
    const int h  = bh & 15;
    const int q0 = qt * QBLK;

    const float LOG2E  = 1.4426950408889634f;
    const float slope2 = exp2f(-0.5f * (float)(h + 1)) * LOG2E;
    const float sc2    = 0.125f * LOG2E;
    float c2[16];
    #pragma unroll
    for (int st = 0; st < 4; ++st)
        #pragma unroll
        for (int rr = 0; rr < 4; ++rr) c2[st * 4 + rr] = (float)(st * 16 + rr) * slope2;

    // ---- Q fragments ----
    bf16x8 qf[2];
    {
        const float* gq = qg + ((size_t)(b * TT + q0 + wv * 16 + qr)) * DDIM + h * HD + hi * 8;
        #pragma unroll
        for (int ch = 0; ch < 2; ++ch) {
            float4 a0 = *(const float4*)(gq + ch * 32);
            float4 a1 = *(const float4*)(gq + ch * 32 + 4);
            bf16x8 w;
            w[0]=f2bf(a0.x); w[1]=f2bf(a0.y); w[2]=f2bf(a0.z); w[3]=f2bf(a0.w);
            w[4]=f2bf(a1.x); w[5]=f2bf(a1.y); w[6]=f2bf(a1.z); w[7]=f2bf(a1.w);
            qf[ch] = w;
        }
    }

    const ushort* kb = kbf + (size_t)bh * TT * HD;
    const ushort* vb = vtt + (size_t)bh * HD * TT;

    const int srow = tid >> 2;
    const int sci  = tid & 3;
    const int sw   = srow & 7;

    // incremental staging pointers (strictly descending by KVBLK per issue)
    bf16x8 kr0, kr1, vr0, vr1;
    const ushort* kp = kb + (size_t)((thi - 1) * KVBLK + srow) * HD + sci * 8;
    const ushort* vp = vb + (size_t)srow * TT + (thi - 1) * KVBLK + sci * 8;
    auto stage_issue = [&]() {
        kr0 = *(const bf16x8*)kp;  kr1 = *(const bf16x8*)(kp + 32);
        vr0 = *(const bf16x8*)vp;  vr1 = *(const bf16x8*)(vp + 32);
        kp -= (size_t)KVBLK * HD;  vp -= KVBLK;
    };
    auto stage_write = [&](int nb) {
        *(bf16x8*)&lds_k[nb][srow * 64 + ((sci ^ sw) << 3)]       = kr0;
        *(bf16x8*)&lds_k[nb][srow * 64 + (((sci + 4) ^ sw) << 3)] = kr1;
        *(bf16x8*)&lds_v[nb][srow * 64 + ((sci ^ sw) << 3)]       = vr0;
        *(bf16x8*)&lds_v[nb][srow * 64 + (((sci + 4) ^ sw) << 3)] = vr1;
    };

    stage_issue();
    stage_write(0);

    f32x4 oacc[4] = {};
    float mrun = -INFINITY, lrun = 0.f;
    const int ti = q0 + wv * 16 + qr;

    for (int j = 0; j < nt; ++j) {
        const int buf = j & 1;
        const int kv0 = (thi - 1 - j) * KVBLK;
        if (j + 1 < nt) stage_issue();   // loads stay in flight ACROSS the barrier
        barrier_lgkm_only();

        ushort* pb = &lds_v[buf ^ 1][wv * 1024];   // P slot aliased into idle V buffer
        const bool diag = (j == 0) && hasdiag;

        // ---- S^T = K Q^T ----
        f32x4 sa[4] = {};
        __builtin_amdgcn_s_setprio(1);
        #pragma unroll
        for (int st = 0; st < 4; ++st) {
            if (!diag || st <= wv) {
                const int krow = st * 16 + qr;
                const int ksw = (krow & 7);
                bf16x8 k0 = *(const bf16x8*)&lds_k[buf][krow * 64 + ((hi ^ ksw) << 3)];
                bf16x8 k1 = *(const bf16x8*)&lds_k[buf][krow * 64 + (((4 + hi) ^ ksw) << 3)];
                sa[st] = __builtin_amdgcn_mfma_f32_16x16x32_bf16(k0, qf[0], sa[st], 0, 0, 0);
                sa[st] = __builtin_amdgcn_mfma_f32_16x16x32_bf16(k1, qf[1], sa[st], 0, 0, 0);
            }
        }
        __builtin_amdgcn_s_setprio(0);

        // ---- in-register softmax; exact integer-domain causal mask (R9 lesson) ----
        const float relb  = (float)(kv0 - ti + hi * 4);
        const float relb2 = relb * slope2;
        float xv[16];
        float tm = -INFINITY;
        #pragma unroll
        for (int st = 0; st < 4; ++st)
            #pragma unroll
            for (int rr = 0; rr < 4; ++rr) {
                float v = fmaf(sa[st][rr], sc2, relb2 + c2[st * 4 + rr]);
                if (diag) {
                    const float rel = relb + (float)(st * 16 + rr);   // exact small ints
                    v = (rel <= 0.f) ? v : -INFINITY;
                }
                xv[st * 4 + rr] = v;
                tm = fmaxf(tm, v);
            }
        if (!__all(tm <= mrun + 8.f)) {   // common path: no cross-lane reduce (R12)
            tm = fmaxf(tm, __shfl_xor(tm, 16));
            tm = fmaxf(tm, __shfl_xor(tm, 32));
            const float mnew = fmaxf(mrun, tm);
            const float fsc  = exp2f(mrun - mnew);
            mrun = mnew;
            lrun *= fsc;
            float fo[4];
            #pragma unroll
            for (int rr = 0; rr < 4; ++rr) fo[rr] = __shfl(fsc, hi * 4 + rr);
            #pragma unroll
            for (int dt = 0; dt < 4; ++dt)
                #pragma unroll
                for (int rr = 0; rr < 4; ++rr) oacc[dt][rr] *= fo[rr];
        }
        float psum = 0.f;
        #pragma unroll
        for (int i = 0; i < 16; ++i) { xv[i] = exp2f(xv[i] - mrun); psum += xv[i]; }
        lrun += psum;

        // ---- P -> aliased LDS slot (same-wave producer/consumer) ----
        #pragma unroll
        for (int st = 0; st < 4; ++st) {
            ushort4 w;
            w.x = f2bf(xv[st * 4 + 0]); w.y = f2bf(xv[st * 4 + 1]);
            w.z = f2bf(xv[st * 4 + 2]); w.w = f2bf(xv[st * 4 + 3]);
            const int slot8 = (st << 1) | (hi >> 1);
            *(ushort4*)&pb[qr * 64 + ((slot8 ^ (qr & 7)) << 3) + ((hi & 1) << 2)] = w;
        }

        // ---- O += P V ----
        __builtin_amdgcn_s_setprio(1);
        #pragma unroll
        for (int ks = 0; ks < 2; ++ks) {
            if (!diag || wv >= 2 || ks == 0) {
                bf16x8 pa = *(const bf16x8*)&pb[qr * 64 + ((((ks << 2) | hi) ^ (qr & 7)) << 3)];
                #pragma unroll
                for (int dt = 0; dt < 4; ++dt) {
                    const int dv = dt * 16 + qr;
                    bf16x8 vbf = *(const bf16x8*)&lds_v[buf][dv * 64 + ((((ks << 2) + hi) ^ (dv & 7)) << 3)];
                    oacc[dt] = __builtin_amdgcn_mfma_f32_16x16x32_bf16(pa, vbf, oacc[dt], 0, 0, 0);
                }
            }
        }
        __builtin_amdgcn_s_setprio(0);

        if (j + 1 < nt) stage_write(buf ^ 1);   // overwrites this iter's P slots (safe)
    }

    // ---- epilogue ----
    float lr = lrun;
    lr += __shfl_xor(lr, 16);
    lr += __shfl_xor(lr, 32);
    if (!heavy) {
        const float linv = 1.0f / lr;
        #pragma unroll
        for (int rr = 0; rr < 4; ++rr) {
            const float inv = __shfl(linv, hi * 4 + rr);
            float* go = out + ((size_t)(b * TT + q0 + wv * 16 + hi * 4 + rr)) * DDIM + h * HD;
            #pragma unroll
            for (int dt = 0; dt < 4; ++dt)
                go[dt * 16 + qr] = oacc[dt][rr] * inv;
        }
    } else {
        float* pbase = po + ((size_t)((part * 32 + bh) * 16 + (qt - 16))) * 4096;
        #pragma unroll
        for (int rr = 0; rr < 4; ++rr) {
            const int row = wv * 16 + hi * 4 + rr;
            #pragma unroll
            for (int dt = 0; dt < 4; ++dt)
                pbase[row * 64 + dt * 16 + qr] = oacc[dt][rr];
        }
        if (hi == 0) {
            float* mlb = ml + ((size_t)((part * 32 + bh) * 16 + (qt - 16))) * 128 + (wv * 16 + qr) * 2;
            mlb[0] = mrun;
            mlb[1] = lr;
        }
    }
}

// ============ combine (R12-proven): merge the two kv-halves of heavy tiles ============
__global__ __launch_bounds__(256)
void combine_kernel(const float* __restrict__ po, const float* __restrict__ ml,
                    float* __restrict__ out) {
    const int blk = (int)blockIdx.x;       // 0..511
    const int bh  = blk >> 4;
    const int q16 = blk & 15;
    const int qt  = 16 + q16;
    const int b = bh >> 4, h = bh & 15;
    const int tid = threadIdx.x;
    const int row = tid >> 2;              // 0..63
    const int c0  = (tid & 3) * 16;

    const float* ml0 = ml + ((size_t)((0 * 32 + bh) * 16 + q16)) * 128 + row * 2;
    const float* ml1 = ml + ((size_t)((1 * 32 + bh) * 16 + q16)) * 128 + row * 2;
    const float m0 = ml0[0], l0 = ml0[1];
    const float m1 = ml1[0], l1 = ml1[1];
    const float m  = fmaxf(m0, m1);
    const float a0 = exp2f(m0 - m);
    const float a1 = exp2f(m1 - m);
    const float linv = 1.0f / fmaf(l0, a0, l1 * a1);
    const float s0 = a0 * linv, s1 = a1 * linv;

    const float* p0 = po + ((size_t)((0 * 32 + bh) * 16 + q16) * 64 + row) * 64 + c0;
    const float* p1 = po + ((size_t)((1 * 32 + bh) * 16 + q16) * 64 + row) * 64 + c0;
    float* go = out + ((size_t)(b * TT + qt * 64 + row)) * DDIM + h * HD + c0;
    #pragma unroll
    for (int i = 0; i < 4; ++i) {
        float4 x0 = *(const float4*)(p0 + i * 4);
        float4 x1 = *(const float4*)(p1 + i * 4);
        float4 r;
        r.x = x0.x * s0 + x1.x * s1;
        r.y = x0.y * s0 + x1.y * s1;
        r.z = x0.z * s0 + x1.z * s1;
        r.w = x0.w * s0 + x1.w * s1;
        *(float4*)(go + i * 4) = r;
    }
}

// ============ tier-2 main (R11-proven 62us) if ws < split needs ============
__global__ __launch_bounds__(256, 2)
void attn_main(const float* __restrict__ qg, const ushort* __restrict__ kbf,
               const ushort* __restrict__ vt, float* __restrict__ out) {
    __shared__ __align__(16) ushort lds_k[2][KVBLK * HD];
    __shared__ __align__(16) ushort lds_v[2][HD * KVBLK];
    __shared__ __align__(16) ushort lds_p[4][16 * 64];

    const int tid  = threadIdx.x;
    const int wv   = tid >> 6;
    const int lane = tid & 63;
    const int hi   = lane >> 4;
    const int qr   = lane & 15;

    const int flat = (int)blockIdx.x;
    const int xcd  = flat & 7;
    const int idx  = flat >> 3;
    const int bs   = idx >> 5;
    const int s    = idx & 31;
    const int bh   = xcd * 4 + bs;
    const int qt   = (bs & 1) ? s : (NQT - 1 - s);
    const int b    = bh >> 4;
    const int h    = bh & 15;
    const int q0   = qt * QBLK;

    const float LOG2E  = 1.4426950408889634f;
    const float slope2 = exp2f(-0.5f * (float)(h + 1)) * LOG2E;
    const float sc2    = 0.125f * LOG2E;

    bf16x8 qf[2];
    {
        const float* gq = qg + ((size_t)(b * TT + q0 + wv * 16 + qr)) * DDIM + h * HD + hi * 8;
        #pragma unroll
        for (int ch = 0; ch < 2; ++ch) {
            float4 a0 = *(const float4*)(gq + ch * 32);
            float4 a1 = *(const float4*)(gq + ch * 32 + 4);
            bf16x8 w;
            w[0]=f2bf(a0.x); w[1]=f2bf(a0.y); w[2]=f2bf(a0.z); w[3]=f2bf(a0.w);
            w[4]=f2bf(a1.x); w[5]=f2bf(a1.y); w[6]=f2bf(a1.z); w[7]=f2bf(a1.w);
            qf[ch] = w;
        }
    }

    const ushort* kb = kbf + (size_t)bh * TT * HD;
    const ushort* vb = vt  + (size_t)bh * HD * TT;

    const int srow = tid >> 2;
    const int sci  = tid & 3;

    bf16x8 kr0, kr1, vr0, vr1;
    auto stage_issue = [&](int kv0) {
        const ushort* kp = kb + (size_t)(kv0 + srow) * HD + sci * 8;
        kr0 = *(const bf16x8*)kp;
        kr1 = *(const bf16x8*)(kp + 32);
        const ushort* vp = vb + (size_t)srow * TT + kv0 + sci * 8;
        vr0 = *(const bf16x8*)vp;
        vr1 = *(const bf16x8*)(vp + 32);
    };
    auto stage_write = [&](int nb) {
        const int sw = (srow & 7);
        *(bf16x8*)&lds_k[nb][srow * 64 + ((sci ^ sw) << 3)]       = kr0;
        *(bf16x8*)&lds_k[nb][srow * 64 + (((sci + 4) ^ sw) << 3)] = kr1;
        *(bf16x8*)&lds_v[nb][srow * 64 + ((sci ^ sw) << 3)]       = vr0;
        *(bf16x8*)&lds_v[nb][srow * 64 + (((sci + 4) ^ sw) << 3)] = vr1;
    };

    const int nit = qt + 1;
    stage_issue(q0);
    stage_write(0);

    f32x4 oacc[4] = {};
    float mrun = -INFINITY, lrun = 0.f;
    const int ti = q0 + wv * 16 + qr;

    for (int j = 0; j < nit; ++j) {
        const int buf = j & 1;
        const int kv0 = q0 - j * KVBLK;
        if (j + 1 < nit) stage_issue(kv0 - KVBLK);
        barrier_lgkm_only();

        const bool diag = (j == 0);

        f32x4 sa[4] = {};
        __builtin_amdgcn_s_setprio(1);
        #pragma unroll
        for (int st = 0; st < 4; ++st) {
            if (!diag || st <= wv) {
                const int krow = st * 16 + qr;
                const int sw = (krow & 7);
                bf16x8 k0 = *(const bf16x8*)&lds_k[buf][krow * 64 + ((hi ^ sw) << 3)];
                bf16x8 k1 = *(const bf16x8*)&lds_k[buf][krow * 64 + (((4 + hi) ^ sw) << 3)];
                sa[st] = __builtin_amdgcn_mfma_f32_16x16x32_bf16(k0, qf[0], sa[st], 0, 0, 0);
                sa[st] = __builtin_amdgcn_mfma_f32_16x16x32_bf16(k1, qf[1], sa[st], 0, 0, 0);
            }
        }
        __builtin_amdgcn_s_setprio(0);

        const float relb = (float)(kv0 - ti + hi * 4);
        float xv[16];
        float tm = -INFINITY;
        #pragma unroll
        for (int st = 0; st < 4; ++st)
            #pragma unroll
            for (int rr = 0; rr < 4; ++rr) {
                const float rel = relb + (float)(st * 16 + rr);
                float v = fmaf(sa[st][rr], sc2, rel * slope2);
                if (diag) v = (rel <= 0.f) ? v : -INFINITY;
                xv[st * 4 + rr] = v;
                tm = fmaxf(tm, v);
            }
        tm = fmaxf(tm, __shfl_xor(tm, 16));
        tm = fmaxf(tm, __shfl_xor(tm, 32));
        if (!__all(tm <= mrun + 8.f)) {
            const float mnew = fmaxf(mrun, tm);
            const float fsc  = exp2f(mrun - mnew);
            mrun = mnew;
            lrun *= fsc;
            float fo[4];
            #pragma unroll
            for (int rr = 0; rr < 4; ++rr) fo[rr] = __shfl(fsc, hi * 4 + rr);
            #pragma unroll
            for (int dt = 0; dt < 4; ++dt)
                #pragma unroll
                for (int rr = 0; rr < 4; ++rr) oacc[dt][rr] *= fo[rr];
        }
        float psum = 0.f;
        #pragma unroll
        for (int i = 0; i < 16; ++i) { xv[i] = exp2f(xv[i] - mrun); psum += xv[i]; }
        lrun += psum;

        #pragma unroll
        for (int st = 0; st < 4; ++st) {
            ushort4 w;
            w.x = f2bf(xv[st * 4 + 0]); w.y = f2bf(xv[st * 4 + 1]);
            w.z = f2bf(xv[st * 4 + 2]); w.w = f2bf(xv[st * 4 + 3]);
            const int slot8 = (st << 1) | (hi >> 1);
            *(ushort4*)&lds_p[wv][qr * 64 + ((slot8 ^ (qr & 7)) << 3) + ((hi & 1) << 2)] = w;
        }

        __builtin_amdgcn_s_setprio(1);
        #pragma unroll
        for (int ks = 0; ks < 2; ++ks) {
            if (!diag || wv >= 2 || ks == 0) {
                bf16x8 pa = *(const bf16x8*)&lds_p[wv][qr * 64 + ((((ks << 2) | hi) ^ (qr & 7)) << 3)];
                #pragma unroll
                for (int dt = 0; dt < 4; ++dt) {
                    const int dv = dt * 16 + qr;
                    bf16x8 vbf = *(const bf16x8*)&lds_v[buf][dv * 64 + ((((ks << 2) + hi) ^ (dv & 7)) << 3)];
                    oacc[dt] = __builtin_amdgcn_mfma_f32_16x16x32_bf16(pa, vbf, oacc[dt], 0, 0, 0);
                }
            }
        }
        __builtin_amdgcn_s_setprio(0);

        if (j + 1 < nit) stage_write(buf ^ 1);
    }

    {
        float lr = lrun;
        lr += __shfl_xor(lr, 16);
        lr += __shfl_xor(lr, 32);
        const float linv = 1.0f / lr;
        #pragma unroll
        for (int rr = 0; rr < 4; ++rr) {
            const float inv = __shfl(linv, hi * 4 + rr);
            float* go = out + ((size_t)(b * TT + q0 + wv * 16 + hi * 4 + rr)) * DDIM + h * HD;
            #pragma unroll
            for (int dt = 0; dt < 4; ++dt)
                go[dt * 16 + qr] = oacc[dt][rr] * inv;
        }
    }
}

extern "C" void kernel_launch(void* const* d_in, const int* in_sizes, int n_in,
                              void* d_out, int out_size, void* d_ws, size_t ws_size,
                              hipStream_t stream) {
    (void)in_sizes; (void)n_in; (void)out_size;
    const float* q = (const float*)d_in[0];
    const float* k = (const float*)d_in[1];
    const float* v = (const float*)d_in[2];
    float* o = (float*)d_out;

    const size_t elems   = (size_t)2 * NHEAD * TT * HD;     // 4.19M per tensor
    const size_t kv_b    = 2 * elems * sizeof(ushort);      // 16.78 MB
    const size_t po_b    = (size_t)2 * 32 * 16 * 64 * 64 * sizeof(float);  // 16.78 MB
    const size_t ml_b    = (size_t)2 * 32 * 16 * 64 * 2 * sizeof(float);   // 0.52 MB
    if (ws_size >= kv_b + po_b + ml_b) {
        ushort* kbf = (ushort*)d_ws;
        ushort* vtt = kbf + elems;
        float*  po  = (float*)((char*)d_ws + kv_b);
        float*  ml  = po + (size_t)2 * 32 * 16 * 64 * 64;
        prepass_kernel<<<dim3(32, 32), 256, 0, stream>>>(k, v, kbf, vtt);
        attn_split<<<dim3(1536), 256, 0, stream>>>(q, kbf, vtt, po, ml, o);
        combine_kernel<<<dim3(512), 256, 0, stream>>>(po, ml, o);
    } else if (ws_size >= kv_b) {
        ushort* kbf = (ushort*)d_ws;
        ushort* vtt = kbf + elems;
        prepass_kernel<<<dim3(32, 32), 256, 0, stream>>>(k, v, kbf, vtt);
        attn_main<<<dim3(1024), 256, 0, stream>>>(q, kbf, vtt, o);
    }
}